// Round 1
// baseline (100.563 us; speedup 1.0000x reference)
//
#include <hip/hip_runtime.h>

// One wavefront (64 lanes) simulates one 9-qubit patch circuit.
// Flat amplitude index f in [0,512): bit q of f == qubit q (little-endian,
// matches the reference's axis mapping ax = NQ - q).
// Lane l holds amplitudes f = l*8 + r, r in [0,8):
//   qubits 0..2  -> bits of r   (in-register)
//   qubits 3..8  -> bits of lane (cross-lane via shfl_xor)

__device__ __forceinline__ float shx(float v, int m) { return __shfl_xor(v, m, 64); }

// ---------------- RY(theta): [[c,-s],[s,c]] ----------------
template <int Q>
__device__ __forceinline__ void RYg(float (&re)[8], float (&im)[8], float c, float s, int lane) {
    if constexpr (Q < 3) {
        constexpr int st = 1 << Q;
#pragma unroll
        for (int r0 = 0; r0 < 8; ++r0) {
            if (r0 & st) continue;
            const int r1 = r0 | st;
            float a = re[r0], b = re[r1];
            re[r0] = c * a - s * b; re[r1] = s * a + c * b;
            a = im[r0]; b = im[r1];
            im[r0] = c * a - s * b; im[r1] = s * a + c * b;
        }
    } else {
        constexpr int lm = 1 << (Q - 3);
        const float sg = (lane & lm) ? s : -s;  // bit0: c*own - s*other ; bit1: c*own + s*other
#pragma unroll
        for (int r = 0; r < 8; ++r) {
            const float orr = shx(re[r], lm);
            const float oii = shx(im[r], lm);
            re[r] = c * re[r] + sg * orr;
            im[r] = c * im[r] + sg * oii;
        }
    }
}

// ---------------- RZ(theta): diag(e^{-i t/2}, e^{+i t/2}) — always local ----------------
template <int Q>
__device__ __forceinline__ void RZg(float (&re)[8], float (&im)[8], float c, float s, int lane) {
    if constexpr (Q < 3) {
#pragma unroll
        for (int r = 0; r < 8; ++r) {
            const float sg = ((r >> Q) & 1) ? s : -s;
            const float a = re[r], b = im[r];
            re[r] = c * a - sg * b;
            im[r] = c * b + sg * a;
        }
    } else {
        const float sg = ((lane >> (Q - 3)) & 1) ? s : -s;
#pragma unroll
        for (int r = 0; r < 8; ++r) {
            const float a = re[r], b = im[r];
            re[r] = c * a - sg * b;
            im[r] = c * b + sg * a;
        }
    }
}

// ---------------- CX(c,t): flip bit t where bit c == 1 ----------------
template <int C, int T>
__device__ __forceinline__ void CXg(float (&re)[8], float (&im)[8], int lane) {
    if constexpr (C < 3 && T < 3) {
        constexpr int cm = 1 << C, tm = 1 << T;
#pragma unroll
        for (int r0 = 0; r0 < 8; ++r0) {
            if (!(r0 & cm) || (r0 & tm)) continue;
            const int r1 = r0 | tm;
            float t = re[r0]; re[r0] = re[r1]; re[r1] = t;
            t = im[r0]; im[r0] = im[r1]; im[r1] = t;
        }
    } else if constexpr (C < 3 && T >= 3) {
        constexpr int cm = 1 << C, lm = 1 << (T - 3);
#pragma unroll
        for (int r = 0; r < 8; ++r) {
            const float orr = shx(re[r], lm);
            const float oii = shx(im[r], lm);
            if (r & cm) { re[r] = orr; im[r] = oii; }
        }
    } else if constexpr (C >= 3 && T < 3) {
        constexpr int cm = 1 << (C - 3), tm = 1 << T;
        const bool ctl = (lane & cm) != 0;
#pragma unroll
        for (int r0 = 0; r0 < 8; ++r0) {
            if (r0 & tm) continue;
            const int r1 = r0 | tm;
            float a0 = re[r0], a1 = re[r1];
            re[r0] = ctl ? a1 : a0; re[r1] = ctl ? a0 : a1;
            a0 = im[r0]; a1 = im[r1];
            im[r0] = ctl ? a1 : a0; im[r1] = ctl ? a0 : a1;
        }
    } else {
        constexpr int cm = 1 << (C - 3), lm = 1 << (T - 3);
        const bool ctl = (lane & cm) != 0;
#pragma unroll
        for (int r = 0; r < 8; ++r) {
            const float orr = shx(re[r], lm);
            const float oii = shx(im[r], lm);
            if (ctl) { re[r] = orr; im[r] = oii; }
        }
    }
}

// ---------------- CRX(c,t): where bit c==1, apply [[co,-i si],[-i si,co]] on bit t ----
// Both halves of the target pair: new = co*own + si*(im_other, -re_other)
template <int C, int T>
__device__ __forceinline__ void CRXg(float (&re)[8], float (&im)[8], float co, float si, int lane) {
    if constexpr (C < 3 && T < 3) {
        constexpr int cm = 1 << C, tm = 1 << T;
#pragma unroll
        for (int r0 = 0; r0 < 8; ++r0) {
            if (!(r0 & cm) || (r0 & tm)) continue;
            const int r1 = r0 | tm;
            const float r0r = re[r0], r0i = im[r0], r1r = re[r1], r1i = im[r1];
            re[r0] = co * r0r + si * r1i;
            im[r0] = co * r0i - si * r1r;
            re[r1] = co * r1r + si * r0i;
            im[r1] = co * r1i - si * r0r;
        }
    } else if constexpr (C >= 3 && T < 3) {
        constexpr int cm = 1 << (C - 3), tm = 1 << T;
        const bool ctl = (lane & cm) != 0;
#pragma unroll
        for (int r0 = 0; r0 < 8; ++r0) {
            if (r0 & tm) continue;
            const int r1 = r0 | tm;
            const float r0r = re[r0], r0i = im[r0], r1r = re[r1], r1i = im[r1];
            const float n0r = co * r0r + si * r1i, n0i = co * r0i - si * r1r;
            const float n1r = co * r1r + si * r0i, n1i = co * r1i - si * r0r;
            if (ctl) { re[r0] = n0r; im[r0] = n0i; re[r1] = n1r; im[r1] = n1i; }
        }
    } else if constexpr (C >= 3 && T >= 3) {
        constexpr int cm = 1 << (C - 3), lm = 1 << (T - 3);
        const bool ctl = (lane & cm) != 0;
#pragma unroll
        for (int r = 0; r < 8; ++r) {
            const float orr = shx(re[r], lm);
            const float oii = shx(im[r], lm);
            const float nr = co * re[r] + si * oii;
            const float ni = co * im[r] - si * orr;
            if (ctl) { re[r] = nr; im[r] = ni; }
        }
    } else {  // C < 3, T >= 3 (unused in this circuit, kept for completeness)
        constexpr int cm = 1 << C, lm = 1 << (T - 3);
#pragma unroll
        for (int r = 0; r < 8; ++r) {
            const float orr = shx(re[r], lm);
            const float oii = shx(im[r], lm);
            if (r & cm) {
                const float nr = co * re[r] + si * oii;
                const float ni = co * im[r] - si * orr;
                re[r] = nr; im[r] = ni;
            }
        }
    }
}

// Precompute cos(w/2), sin(w/2) for the 42 shared weights.
__global__ void prep_kernel(const float* __restrict__ w, float2* __restrict__ wcs) {
    const int t = threadIdx.x;
    if (t < 42) {
        float s, c;
        sincosf(w[t] * 0.5f, &s, &c);
        wcs[t] = make_float2(c, s);
    }
}

// 4 waves per block, one patch per wave.
__global__ __launch_bounds__(256) void qcnn_kernel(const float* __restrict__ x,
                                                   const float2* __restrict__ wcs,
                                                   float* __restrict__ feats) {
    __shared__ float2 lw[42];
    const int tid = threadIdx.x;
    if (tid < 42) lw[tid] = wcs[tid];
    __syncthreads();

    const int lane = tid & 63;
    const unsigned p = blockIdx.x * 4u + (tid >> 6);   // patch id, < B*676 (grid exact)
    const unsigned b = p / 676u;
    const unsigned rem = p - b * 676u;
    const unsigned i = rem / 26u;
    const unsigned j = rem - i * 26u;
    const float* xb = x + b * 784u;

    // Encoding angles: lane k (k<9) computes sincos(x[i+k/3, j+k%3] * pi/2)
    float c_enc = 1.0f, s_enc = 0.0f;
    if (lane < 9) {
        const int di = lane / 3, dj = lane - di * 3;
        const float ang = xb[(i + di) * 28u + (j + dj)] * 1.57079632679489662f; // pi/2
        sincosf(ang, &s_enc, &c_enc);
    }

    float re[8], im[8];
#pragma unroll
    for (int r = 0; r < 8; ++r) { re[r] = 0.0f; im[r] = 0.0f; }
    if (lane == 0) re[0] = 1.0f;   // |0...0>

    // --- input encoding: RY(q, angle_q) ---
    {
        float c, s;
#define ENC(Q) c = __shfl(c_enc, Q, 64); s = __shfl(s_enc, Q, 64); RYg<Q>(re, im, c, s, lane);
        ENC(0) ENC(1) ENC(2) ENC(3) ENC(4) ENC(5) ENC(6) ENC(7) ENC(8)
#undef ENC
    }

#define W(idx) lw[idx].x, lw[idx].y
    // conv1: RY all 9, RZ all 9
    RYg<0>(re, im, W(0), lane); RYg<1>(re, im, W(1), lane); RYg<2>(re, im, W(2), lane);
    RYg<3>(re, im, W(3), lane); RYg<4>(re, im, W(4), lane); RYg<5>(re, im, W(5), lane);
    RYg<6>(re, im, W(6), lane); RYg<7>(re, im, W(7), lane); RYg<8>(re, im, W(8), lane);
    RZg<0>(re, im, W(9), lane); RZg<1>(re, im, W(10), lane); RZg<2>(re, im, W(11), lane);
    RZg<3>(re, im, W(12), lane); RZg<4>(re, im, W(13), lane); RZg<5>(re, im, W(14), lane);
    RZg<6>(re, im, W(15), lane); RZg<7>(re, im, W(16), lane); RZg<8>(re, im, W(17), lane);
    // ring CNOT
    CXg<0, 1>(re, im, lane); CXg<1, 2>(re, im, lane); CXg<2, 3>(re, im, lane);
    CXg<3, 4>(re, im, lane); CXg<4, 5>(re, im, lane); CXg<5, 6>(re, im, lane);
    CXg<6, 7>(re, im, lane); CXg<7, 8>(re, im, lane); CXg<8, 0>(re, im, lane);
    // pool1
    CRXg<1, 0>(re, im, W(18), lane); CRXg<2, 0>(re, im, W(19), lane);
    CRXg<4, 3>(re, im, W(20), lane); CRXg<5, 3>(re, im, W(21), lane);
    CRXg<7, 6>(re, im, W(22), lane); CRXg<8, 6>(re, im, W(23), lane);
    // conv2 on {0,3,6}
    RYg<0>(re, im, W(24), lane); RYg<3>(re, im, W(25), lane); RYg<6>(re, im, W(26), lane);
    RZg<0>(re, im, W(27), lane); RZg<3>(re, im, W(28), lane); RZg<6>(re, im, W(29), lane);
    CXg<0, 3>(re, im, lane); CXg<3, 6>(re, im, lane); CXg<6, 0>(re, im, lane);
    RYg<0>(re, im, W(30), lane); RZg<3>(re, im, W(31), lane);
    // pool2
    CRXg<3, 0>(re, im, W(32), lane); CRXg<3, 6>(re, im, W(33), lane);
    RYg<0>(re, im, W(34), lane); RYg<6>(re, im, W(35), lane);
    // conv3
    RYg<0>(re, im, W(36), lane); RYg<6>(re, im, W(37), lane);
    CXg<0, 6>(re, im, lane);
    RZg<0>(re, im, W(38), lane); RZg<6>(re, im, W(39), lane);
    // pool3
    CRXg<6, 0>(re, im, W(40), lane);
    RYg<0>(re, im, W(41), lane);
#undef W

    // Expectations on qubit 0 (bit 0 of r): pairs (r, r+1)
    float zr = 0.0f, zi = 0.0f, ez = 0.0f;
#pragma unroll
    for (int r0 = 0; r0 < 8; r0 += 2) {
        const int r1 = r0 + 1;
        zr += re[r0] * re[r1] + im[r0] * im[r1];
        zi += re[r0] * im[r1] - im[r0] * re[r1];
        ez += re[r0] * re[r0] + im[r0] * im[r0] - re[r1] * re[r1] - im[r1] * im[r1];
    }
#pragma unroll
    for (int m = 1; m < 64; m <<= 1) {
        zr += shx(zr, m); zi += shx(zi, m); ez += shx(ez, m);
    }
    if (lane == 0) {
        feats[p * 3u + 0u] = 2.0f * zr;   // <X>
        feats[p * 3u + 1u] = 2.0f * zi;   // <Y>
        feats[p * 3u + 2u] = ez;          // <Z>
    }
}

// out[b,c] = fc_b[c] + dot(feats[b,:], fc_w[c,:]), 2028-long dot per block.
__global__ __launch_bounds__(256) void fc_kernel(const float* __restrict__ feats,
                                                 const float* __restrict__ fc_w,
                                                 const float* __restrict__ fc_b,
                                                 float* __restrict__ out) {
    const int b = blockIdx.x / 10, c = blockIdx.x - b * 10;
    const float* f = feats + b * 2028;
    const float* wr = fc_w + c * 2028;
    float acc = 0.0f;
    for (int k = threadIdx.x; k < 2028; k += 256) acc += f[k] * wr[k];
#pragma unroll
    for (int m = 1; m < 64; m <<= 1) acc += __shfl_xor(acc, m, 64);
    __shared__ float sbuf[4];
    const int lane = threadIdx.x & 63, wv = threadIdx.x >> 6;
    if (lane == 0) sbuf[wv] = acc;
    __syncthreads();
    if (threadIdx.x == 0) out[b * 10 + c] = sbuf[0] + sbuf[1] + sbuf[2] + sbuf[3] + fc_b[c];
}

extern "C" void kernel_launch(void* const* d_in, const int* in_sizes, int n_in,
                              void* d_out, int out_size, void* d_ws, size_t ws_size,
                              hipStream_t stream) {
    const float* x    = (const float*)d_in[0];   // (B,1,28,28)
    const float* w    = (const float*)d_in[1];   // (42,)
    const float* fc_w = (const float*)d_in[2];   // (10, 2028)
    const float* fc_b = (const float*)d_in[3];   // (10,)
    float* out = (float*)d_out;                  // (B, 10)

    const int B = in_sizes[0] / 784;             // 8
    const int npatch = B * 676;                  // 5408

    // ws layout: [0..42) float2 wcs | feats at 128-float offset (alignment)
    float2* wcs  = (float2*)d_ws;
    float* feats = (float*)d_ws + 128;           // npatch*3 floats

    prep_kernel<<<1, 64, 0, stream>>>(w, wcs);
    qcnn_kernel<<<npatch / 4, 256, 0, stream>>>(x, wcs, feats);
    fc_kernel<<<B * 10, 256, 0, stream>>>(feats, fc_w, fc_b, out);
}